// Round 4
// baseline (160.875 us; speedup 1.0000x reference)
//
#include <hip/hip_runtime.h>

// Round 4: occupancy round. Both kernels were grid-limited to 2 blocks/CU
// (512 blocks); both are latency-bound (issue math says ~5 us each, measured
// ~40 us each). Changes:
//  - attn: un-paired q-tiles, grid (8,128)=1024 blocks, qt = 7-blockIdx.x so
//    heavy blocks dispatch first (causal imbalance backfilled by scheduler).
//  - gate_qkv: 64 rows/block (wave-private 16-row m-tiles), grid 1024,
//    ONE barrier total; V epilogue parks C-frags in dead xg LDS rows
//    (wave-private, no barrier) then stores vT with b128 writes.
//  - rcp via __builtin_amdgcn_rcpf (tol 5.7e-2 >> rcp err).
// Fixed harness overhead in dur_us: ~55 us (268 MB ws re-poison + restores).
// ws: q,k,vT bf16 (25.2 MB) + bf16 weights (80 KB).

#define BB 128
#define TB 512
#define CC 128
#define HH 64

static constexpr float SCALE = 0.088388347648318447f; // C^-0.5 (NOT H^-0.5)

typedef __attribute__((ext_vector_type(8))) short bf16x8;
typedef __attribute__((ext_vector_type(8))) unsigned short u16x8;
typedef __attribute__((ext_vector_type(4))) float f32x4;

__device__ inline unsigned short f2bf(float f) {
    union { float f; unsigned u; } x; x.f = f;
    unsigned r = x.u + 0x7fff + ((x.u >> 16) & 1);   // RNE
    return (unsigned short)(r >> 16);
}
__device__ inline float bf2f(unsigned short h) {
    union { unsigned u; float f; } x; x.u = ((unsigned)h) << 16;
    return x.f;
}

// ---- weight transpose+convert: WT[n][k] = bf16(W[k][n]) ----
__global__ void prep_weights(const float* __restrict__ Wg, const float* __restrict__ Wk,
                             const float* __restrict__ Wq, const float* __restrict__ Wv,
                             unsigned short* __restrict__ WgT, unsigned short* __restrict__ WkT,
                             unsigned short* __restrict__ WqT, unsigned short* __restrict__ WvT)
{
    int idx = blockIdx.x * 256 + threadIdx.x;        // 0..40959
    if (idx < 16384) {                               // Wg 128x128
        int n = idx >> 7, k = idx & 127;
        WgT[idx] = f2bf(Wg[k * CC + n]);
    } else {
        int j = idx - 16384;                         // 3 x (64x128)
        int mtx = j >> 13;
        int r = j & 8191;
        int n = r >> 7, k = r & 127;
        const float* W = (mtx == 0) ? Wk : (mtx == 1) ? Wq : Wv;
        unsigned short* WT = (mtx == 0) ? WkT : (mtx == 1) ? WqT : WvT;
        WT[r] = f2bf(W[k * HH + n]);
    }
}

__global__ __launch_bounds__(256, 4) void gate_qkv_kernel(
    const float* __restrict__ x, const float* __restrict__ bg,
    const unsigned short* __restrict__ WgT, const unsigned short* __restrict__ WkT,
    const unsigned short* __restrict__ WqT, const unsigned short* __restrict__ WvT,
    unsigned short* __restrict__ qo, unsigned short* __restrict__ ko,
    unsigned short* __restrict__ vto)
{
    __shared__ unsigned short xsb[64 * 136];    // x -> xg in-place; V park reuses rows

    const int tid  = threadIdx.x;
    const int wv   = tid >> 6;
    const int lane = tid & 63;
    const int l15  = lane & 15;
    const int quad = lane >> 4;
    const int R0   = blockIdx.x * 64;           // 64 | 512: block never straddles a batch

    // ---- stage x -> bf16 LDS (only barrier-dependent phase) ----
#pragma unroll
    for (int it = 0; it < 8; ++it) {
        int fid = tid + 256 * it;               // 2048 float4s
        int r = fid >> 5, c4 = fid & 31;
        float4 xv = *(const float4*)(x + (size_t)(R0 + r) * CC + c4 * 4);
        ushort4 h;
        h.x = f2bf(xv.x); h.y = f2bf(xv.y); h.z = f2bf(xv.z); h.w = f2bf(xv.w);
        *(ushort4*)(xsb + r * 136 + c4 * 4) = h;
    }
    __syncthreads();                            // the ONLY barrier

    const int m = 16 * wv + l15;                // this wave owns rows 16wv..16wv+15

    // ---- B-frags: wave-own 16 x-rows (4 k-chunks) ----
    bf16x8 bx[4];
#pragma unroll
    for (int kc = 0; kc < 4; ++kc)
        bx[kc] = *(const bf16x8*)(xsb + m * 136 + kc * 32 + quad * 8);

    // ---- gate GEMM: D'[n][m], n-tiles 0..7 ----
    f32x4 acc[8];
#pragma unroll
    for (int nt = 0; nt < 8; ++nt) acc[nt] = (f32x4){0.f, 0.f, 0.f, 0.f};
#pragma unroll
    for (int nt = 0; nt < 8; ++nt) {
#pragma unroll
        for (int kc = 0; kc < 4; ++kc) {
            bf16x8 aw = *(const bf16x8*)(WgT + (16 * nt + l15) * CC + kc * 32 + quad * 8);
            acc[nt] = __builtin_amdgcn_mfma_f32_16x16x32_bf16(aw, bx[kc], acc[nt], 0, 0, 0);
        }
    }

    // ---- gate epilogue: xg = x*sigmoid(s), in-place, wave-private rows ----
#pragma unroll
    for (int nt = 0; nt < 8; ++nt) {
        float4 bgv = *(const float4*)(bg + 16 * nt + quad * 4);
        unsigned short* p = xsb + m * 136 + 16 * nt + quad * 4;
        ushort4 xb = *(const ushort4*)p;
        float e0 = __expf(-(acc[nt][0] + bgv.x));
        float e1 = __expf(-(acc[nt][1] + bgv.y));
        float e2 = __expf(-(acc[nt][2] + bgv.z));
        float e3 = __expf(-(acc[nt][3] + bgv.w));
        ushort4 o;
        o.x = f2bf(bf2f(xb.x) * __builtin_amdgcn_rcpf(1.f + e0));
        o.y = f2bf(bf2f(xb.y) * __builtin_amdgcn_rcpf(1.f + e1));
        o.z = f2bf(bf2f(xb.z) * __builtin_amdgcn_rcpf(1.f + e2));
        o.w = f2bf(bf2f(xb.w) * __builtin_amdgcn_rcpf(1.f + e3));
        *(ushort4*)p = o;
    }
    // no barrier: rows are wave-private; compiler orders LDS ops via lgkmcnt

    // ---- reload B-frags (now xg) ----
#pragma unroll
    for (int kc = 0; kc < 4; ++kc)
        bx[kc] = *(const bf16x8*)(xsb + m * 136 + kc * 32 + quad * 8);

    const int b = R0 >> 9, t0 = R0 & 511;
    // ---- q/k/v projections ----
    for (int pj = 0; pj < 3; ++pj) {
        const unsigned short* WT = (pj == 0) ? WkT : (pj == 1) ? WqT : WvT;
        f32x4 pacc[4];
#pragma unroll
        for (int nt = 0; nt < 4; ++nt) pacc[nt] = (f32x4){0.f, 0.f, 0.f, 0.f};
#pragma unroll
        for (int nt = 0; nt < 4; ++nt) {
#pragma unroll
            for (int kc = 0; kc < 4; ++kc) {
                bf16x8 aw = *(const bf16x8*)(WT + (16 * nt + l15) * CC + kc * 32 + quad * 8);
                pacc[nt] = __builtin_amdgcn_mfma_f32_16x16x32_bf16(aw, bx[kc], pacc[nt], 0, 0, 0);
            }
        }

        if (pj < 2) {
            unsigned short* O = (pj == 0) ? ko : qo;
#pragma unroll
            for (int nt = 0; nt < 4; ++nt) {
                ushort4 h;
                h.x = f2bf(pacc[nt][0]); h.y = f2bf(pacc[nt][1]);
                h.z = f2bf(pacc[nt][2]); h.w = f2bf(pacc[nt][3]);
                *(ushort4*)(O + (size_t)(R0 + m) * HH + 16 * nt + quad * 4) = h;
            }
        } else {
            // V: park C' (h-contiguous per lane) into dead xg rows (wave-private),
            // then emit vT[b][h][t] with b128 stores.
#pragma unroll
            for (int nt = 0; nt < 4; ++nt) {
                ushort4 h;
                h.x = f2bf(pacc[nt][0]); h.y = f2bf(pacc[nt][1]);
                h.z = f2bf(pacc[nt][2]); h.w = f2bf(pacc[nt][3]);
                *(ushort4*)(xsb + m * 136 + 16 * nt + quad * 4) = h;  // park[t=m][h]
            }
            // read back: this wave's rows tloc = 16*wv + j (same wave-private set)
            const int h = tid & 63, tc = tid >> 6;     // tc == wv
            u16x8 v0, v1;
#pragma unroll
            for (int j = 0; j < 8; ++j) {
                v0[j] = xsb[(16 * tc + j) * 136 + h];
                v1[j] = xsb[(16 * tc + 8 + j) * 136 + h];
            }
            unsigned short* dst = vto + (size_t)b * (HH * TB) + h * TB + t0 + 16 * tc;
            *(u16x8*)(dst)     = v0;
            *(u16x8*)(dst + 8) = v1;
        }
    }
}

__global__ __launch_bounds__(256, 4) void attn_kernel(
    const unsigned short* __restrict__ q, const unsigned short* __restrict__ k,
    const unsigned short* __restrict__ vt, float* __restrict__ out)
{
    __shared__ unsigned short ks[64 * 72];   // K tile, row-major [t][h]
    __shared__ unsigned short vs[64 * 72];   // vT tile, [h][t]
    __shared__ unsigned short ps[64 * 76];   // P round-trip, rows 16*wave..

    const int tid  = threadIdx.x;
    const int wave = tid >> 6;
    const int lane = tid & 63;
    const int l15  = lane & 15;
    const int quad = lane >> 4;
    const int qt   = 7 - blockIdx.x;         // heavy q-tiles dispatch first
    const int b    = blockIdx.y;
    const int q0   = qt * 64;
    const size_t base = (size_t)b * TB * HH;

    const unsigned short* qrow = q + base + (size_t)(q0 + 16 * wave + l15) * HH;
    bf16x8 aq0 = *(const bf16x8*)(qrow + quad * 8);
    bf16x8 aq1 = *(const bf16x8*)(qrow + 32 + quad * 8);

    f32x4 o4[4];
    float mrow[4], lrow[4];
#pragma unroll
    for (int nt = 0; nt < 4; ++nt) o4[nt] = (f32x4){0.f, 0.f, 0.f, 0.f};
#pragma unroll
    for (int r = 0; r < 4; ++r) { mrow[r] = -1e30f; lrow[r] = 0.f; }

    for (int kt = 0; kt <= qt; ++kt) {
        const int k0 = kt * 64;
        __syncthreads();
#pragma unroll
        for (int i = 0; i < 2; ++i) {
            int cid = tid + 256 * i;
            int r = cid >> 3, c8 = cid & 7;
            *(bf16x8*)(ks + r * 72 + c8 * 8) =
                *(const bf16x8*)(k + base + (size_t)(k0 + r) * HH + c8 * 8);
            *(bf16x8*)(vs + r * 72 + c8 * 8) =
                *(const bf16x8*)(vt + base + (size_t)r * TB + k0 + c8 * 8);
        }
        __syncthreads();

        f32x4 s[4];
#pragma unroll
        for (int nt = 0; nt < 4; ++nt) {
            bf16x8 bk0 = *(const bf16x8*)(ks + (16 * nt + l15) * 72 + quad * 8);
            bf16x8 bk1 = *(const bf16x8*)(ks + (16 * nt + l15) * 72 + 32 + quad * 8);
            f32x4 z = (f32x4){0.f, 0.f, 0.f, 0.f};
            z = __builtin_amdgcn_mfma_f32_16x16x32_bf16(aq0, bk0, z, 0, 0, 0);
            z = __builtin_amdgcn_mfma_f32_16x16x32_bf16(aq1, bk1, z, 0, 0, 0);
            s[nt] = z;
        }

        const bool diag = (kt == qt);
        float mx[4];
#pragma unroll
        for (int r = 0; r < 4; ++r) mx[r] = -1e30f;
#pragma unroll
        for (int nt = 0; nt < 4; ++nt)
#pragma unroll
            for (int r = 0; r < 4; ++r) {
                float sv = s[nt][r] * SCALE;
                if (diag && (16 * nt + l15) > (16 * wave + quad * 4 + r)) sv = -1e30f;
                s[nt][r] = sv;
                mx[r] = fmaxf(mx[r], sv);
            }

#pragma unroll
        for (int r = 0; r < 4; ++r) {
            mx[r] = fmaxf(mx[r], __shfl_xor(mx[r], 1));
            mx[r] = fmaxf(mx[r], __shfl_xor(mx[r], 2));
            mx[r] = fmaxf(mx[r], __shfl_xor(mx[r], 4));
            mx[r] = fmaxf(mx[r], __shfl_xor(mx[r], 8));
        }
        float alpha[4], psum[4];
#pragma unroll
        for (int r = 0; r < 4; ++r) {
            float mn = fmaxf(mrow[r], mx[r]);
            alpha[r] = __expf(mrow[r] - mn);
            mrow[r] = mn;
            psum[r] = 0.f;
        }
#pragma unroll
        for (int nt = 0; nt < 4; ++nt)
#pragma unroll
            for (int r = 0; r < 4; ++r) {
                float e = __expf(s[nt][r] - mrow[r]);
                psum[r] += e;
                ps[(16 * wave + quad * 4 + r) * 76 + 16 * nt + l15] = f2bf(e);
            }
#pragma unroll
        for (int r = 0; r < 4; ++r) {
            psum[r] += __shfl_xor(psum[r], 1);
            psum[r] += __shfl_xor(psum[r], 2);
            psum[r] += __shfl_xor(psum[r], 4);
            psum[r] += __shfl_xor(psum[r], 8);
            lrow[r] = lrow[r] * alpha[r] + psum[r];
        }
#pragma unroll
        for (int nt = 0; nt < 4; ++nt)
#pragma unroll
            for (int r = 0; r < 4; ++r) o4[nt][r] *= alpha[r];

        bf16x8 ap0 = *(const bf16x8*)(ps + (16 * wave + l15) * 76 + quad * 8);
        bf16x8 ap1 = *(const bf16x8*)(ps + (16 * wave + l15) * 76 + 32 + quad * 8);
#pragma unroll
        for (int nt = 0; nt < 4; ++nt) {
            bf16x8 bv0 = *(const bf16x8*)(vs + (16 * nt + l15) * 72 + quad * 8);
            bf16x8 bv1 = *(const bf16x8*)(vs + (16 * nt + l15) * 72 + 32 + quad * 8);
            o4[nt] = __builtin_amdgcn_mfma_f32_16x16x32_bf16(ap0, bv0, o4[nt], 0, 0, 0);
            o4[nt] = __builtin_amdgcn_mfma_f32_16x16x32_bf16(ap1, bv1, o4[nt], 0, 0, 0);
        }
    }

    float inv[4];
#pragma unroll
    for (int r = 0; r < 4; ++r) inv[r] = __builtin_amdgcn_rcpf(lrow[r]);
#pragma unroll
    for (int nt = 0; nt < 4; ++nt)
#pragma unroll
        for (int r = 0; r < 4; ++r)
            out[base + (size_t)(q0 + 16 * wave + quad * 4 + r) * HH + 16 * nt + l15] =
                o4[nt][r] * inv[r];
}

extern "C" void kernel_launch(void* const* d_in, const int* in_sizes, int n_in,
                              void* d_out, int out_size, void* d_ws, size_t ws_size,
                              hipStream_t stream) {
    const float* x  = (const float*)d_in[0];
    const float* Wg = (const float*)d_in[1];
    const float* bg = (const float*)d_in[2];
    const float* Wk = (const float*)d_in[3];
    const float* Wq = (const float*)d_in[4];
    const float* Wv = (const float*)d_in[5];
    float* out = (float*)d_out;

    unsigned short* ws = (unsigned short*)d_ws;
    const size_t BTH = (size_t)BB * TB * HH;   // 4,194,304
    unsigned short* qo  = ws;
    unsigned short* ko  = ws + BTH;
    unsigned short* vto = ws + 2 * BTH;
    unsigned short* WgT = ws + 3 * BTH;        // 128x128
    unsigned short* WkT = WgT + 16384;         // 64x128 each
    unsigned short* WqT = WkT + 8192;
    unsigned short* WvT = WqT + 8192;          // total ws: 25.25 MB

    hipLaunchKernelGGL(prep_weights, dim3(160), dim3(256), 0, stream,
                       Wg, Wk, Wq, Wv, WgT, WkT, WqT, WvT);
    hipLaunchKernelGGL(gate_qkv_kernel, dim3(BB * TB / 64), dim3(256), 0, stream,
                       x, bg, WgT, WkT, WqT, WvT, qo, ko, vto);
    hipLaunchKernelGGL(attn_kernel, dim3(8, BB), dim3(256), 0, stream,
                       qo, ko, vto, out);
}

// Round 5
// 133.424 us; speedup vs baseline: 1.2057x; 1.2057x over previous
//
#include <hip/hip_runtime.h>

// Round 5: revert to R3 shapes (best: 137.5us) + attn staging prefetch.
//  - gate_qkv: R3 version exactly (128 rows/block, mt=2 A-frag reuse, 512
//    blocks). R4's 64-row split REGRESSED (weight-load chain, not occupancy,
//    is the limiter). rcpf sigmoid kept.
//  - attn: paired q-tiles (qt, 7-qt) -> uniform 9 kv-tiles/block (load balance
//    beat occupancy in R4). NEW: linearized (pass,kt) loop with REGISTER
//    PREFETCH of next K/V tile issued right after the staging barrier, hiding
//    global latency behind S-MFMA/softmax/PV of the current tile (2-barrier
//    reg-prefetch pipeline; attacks the vmcnt(0)-before-barrier drain).
// Fixed harness overhead in dur_us: ~55 us (268 MB ws re-poison).
// ws: q,k,vT bf16 (25.2 MB) + bf16 weights (80 KB).

#define BB 128
#define TB 512
#define CC 128
#define HH 64

static constexpr float SCALE = 0.088388347648318447f; // C^-0.5 (NOT H^-0.5)

typedef __attribute__((ext_vector_type(8))) short bf16x8;
typedef __attribute__((ext_vector_type(8))) unsigned short u16x8;
typedef __attribute__((ext_vector_type(4))) float f32x4;

__device__ inline unsigned short f2bf(float f) {
    union { float f; unsigned u; } x; x.f = f;
    unsigned r = x.u + 0x7fff + ((x.u >> 16) & 1);   // RNE
    return (unsigned short)(r >> 16);
}
__device__ inline float bf2f(unsigned short h) {
    union { unsigned u; float f; } x; x.u = ((unsigned)h) << 16;
    return x.f;
}

// ---- weight transpose+convert: WT[n][k] = bf16(W[k][n]) ----
__global__ void prep_weights(const float* __restrict__ Wg, const float* __restrict__ Wk,
                             const float* __restrict__ Wq, const float* __restrict__ Wv,
                             unsigned short* __restrict__ WgT, unsigned short* __restrict__ WkT,
                             unsigned short* __restrict__ WqT, unsigned short* __restrict__ WvT)
{
    int idx = blockIdx.x * 256 + threadIdx.x;        // 0..40959
    if (idx < 16384) {                               // Wg 128x128
        int n = idx >> 7, k = idx & 127;
        WgT[idx] = f2bf(Wg[k * CC + n]);
    } else {
        int j = idx - 16384;                         // 3 x (64x128)
        int mtx = j >> 13;
        int r = j & 8191;
        int n = r >> 7, k = r & 127;
        const float* W = (mtx == 0) ? Wk : (mtx == 1) ? Wq : Wv;
        unsigned short* WT = (mtx == 0) ? WkT : (mtx == 1) ? WqT : WvT;
        WT[r] = f2bf(W[k * HH + n]);
    }
}

__global__ __launch_bounds__(256, 3) void gate_qkv_kernel(
    const float* __restrict__ x, const float* __restrict__ bg,
    const unsigned short* __restrict__ WgT, const unsigned short* __restrict__ WkT,
    const unsigned short* __restrict__ WqT, const unsigned short* __restrict__ WvT,
    unsigned short* __restrict__ qo, unsigned short* __restrict__ ko,
    unsigned short* __restrict__ vto)
{
    __shared__ unsigned short xsb[128 * 136];   // x tile -> xg in-place (bf16)

    const int tid  = threadIdx.x;
    const int wv   = tid >> 6;
    const int lane = tid & 63;
    const int l15  = lane & 15;
    const int quad = lane >> 4;
    const int R0   = blockIdx.x * 128;          // one batch per block (512%128==0)

    // ---- stage x -> bf16 LDS ----
#pragma unroll
    for (int it = 0; it < 16; ++it) {
        int fid = tid + 256 * it;               // 4096 float4s
        int r = fid >> 5, c4 = fid & 31;
        float4 xv = *(const float4*)(x + (size_t)(R0 + r) * CC + c4 * 4);
        ushort4 h;
        h.x = f2bf(xv.x); h.y = f2bf(xv.y); h.z = f2bf(xv.z); h.w = f2bf(xv.w);
        *(ushort4*)(xsb + r * 136 + c4 * 4) = h;
    }
    __syncthreads();

    // ---- B-frags: this wave's 32 x-rows (2 m-tiles x 4 k-chunks) ----
    bf16x8 bx[2][4];
#pragma unroll
    for (int mt = 0; mt < 2; ++mt)
#pragma unroll
        for (int kc = 0; kc < 4; ++kc)
            bx[mt][kc] = *(const bf16x8*)(xsb + (32 * wv + 16 * mt + l15) * 136 +
                                          kc * 32 + quad * 8);

    // ---- gate GEMM: D'[n][m] ----
    f32x4 acc[8][2];
#pragma unroll
    for (int nt = 0; nt < 8; ++nt)
#pragma unroll
        for (int mt = 0; mt < 2; ++mt) acc[nt][mt] = (f32x4){0.f, 0.f, 0.f, 0.f};

#pragma unroll
    for (int nt = 0; nt < 8; ++nt) {
        bf16x8 aw[4];
#pragma unroll
        for (int kc = 0; kc < 4; ++kc)
            aw[kc] = *(const bf16x8*)(WgT + (16 * nt + l15) * CC + kc * 32 + quad * 8);
#pragma unroll
        for (int mt = 0; mt < 2; ++mt)
#pragma unroll
            for (int kc = 0; kc < 4; ++kc)
                acc[nt][mt] = __builtin_amdgcn_mfma_f32_16x16x32_bf16(
                    aw[kc], bx[mt][kc], acc[nt][mt], 0, 0, 0);
    }

    // ---- gate epilogue: xg = x*sigmoid(s), in-place (wave-private rows) ----
#pragma unroll
    for (int nt = 0; nt < 8; ++nt) {
        float4 bgv = *(const float4*)(bg + 16 * nt + quad * 4);
#pragma unroll
        for (int mt = 0; mt < 2; ++mt) {
            int m = 32 * wv + 16 * mt + l15;
            unsigned short* p = xsb + m * 136 + 16 * nt + quad * 4;
            ushort4 xb = *(const ushort4*)p;
            float e0 = __expf(-(acc[nt][mt][0] + bgv.x));
            float e1 = __expf(-(acc[nt][mt][1] + bgv.y));
            float e2 = __expf(-(acc[nt][mt][2] + bgv.z));
            float e3 = __expf(-(acc[nt][mt][3] + bgv.w));
            ushort4 o;
            o.x = f2bf(bf2f(xb.x) * __builtin_amdgcn_rcpf(1.f + e0));
            o.y = f2bf(bf2f(xb.y) * __builtin_amdgcn_rcpf(1.f + e1));
            o.z = f2bf(bf2f(xb.z) * __builtin_amdgcn_rcpf(1.f + e2));
            o.w = f2bf(bf2f(xb.w) * __builtin_amdgcn_rcpf(1.f + e3));
            *(ushort4*)p = o;
        }
    }
    __syncthreads();   // xg visible (cross-lane frag reads next)

    // ---- reload B-frags (now xg) ----
#pragma unroll
    for (int mt = 0; mt < 2; ++mt)
#pragma unroll
        for (int kc = 0; kc < 4; ++kc)
            bx[mt][kc] = *(const bf16x8*)(xsb + (32 * wv + 16 * mt + l15) * 136 +
                                          kc * 32 + quad * 8);

    // ---- q/k/v projections ----
    const int b = R0 >> 9, t0 = R0 & 511;
    for (int pj = 0; pj < 3; ++pj) {
        const unsigned short* WT = (pj == 0) ? WkT : (pj == 1) ? WqT : WvT;
        f32x4 pacc[4][2];
#pragma unroll
        for (int nt = 0; nt < 4; ++nt)
#pragma unroll
            for (int mt = 0; mt < 2; ++mt) pacc[nt][mt] = (f32x4){0.f, 0.f, 0.f, 0.f};

#pragma unroll
        for (int nt = 0; nt < 4; ++nt) {
            bf16x8 aw[4];
#pragma unroll
            for (int kc = 0; kc < 4; ++kc)
                aw[kc] = *(const bf16x8*)(WT + (16 * nt + l15) * CC + kc * 32 + quad * 8);
#pragma unroll
            for (int mt = 0; mt < 2; ++mt)
#pragma unroll
                for (int kc = 0; kc < 4; ++kc)
                    pacc[nt][mt] = __builtin_amdgcn_mfma_f32_16x16x32_bf16(
                        aw[kc], bx[mt][kc], pacc[nt][mt], 0, 0, 0);
        }

        if (pj < 2) {
            unsigned short* O = (pj == 0) ? ko : qo;
#pragma unroll
            for (int nt = 0; nt < 4; ++nt)
#pragma unroll
                for (int mt = 0; mt < 2; ++mt) {
                    int m = 32 * wv + 16 * mt + l15;
                    ushort4 h;
                    h.x = f2bf(pacc[nt][mt][0]); h.y = f2bf(pacc[nt][mt][1]);
                    h.z = f2bf(pacc[nt][mt][2]); h.w = f2bf(pacc[nt][mt][3]);
                    *(ushort4*)(O + (size_t)(R0 + m) * HH + 16 * nt + quad * 4) = h;
                }
        } else {
            // C' layout IS vT: lane holds h = 16nt+quad*4+r, t = t0 + m
#pragma unroll
            for (int nt = 0; nt < 4; ++nt)
#pragma unroll
                for (int mt = 0; mt < 2; ++mt) {
                    int m = 32 * wv + 16 * mt + l15;
                    unsigned short* dst =
                        vto + (size_t)b * (HH * TB) + (16 * nt + quad * 4) * TB + t0 + m;
#pragma unroll
                    for (int r = 0; r < 4; ++r)
                        dst[r * TB] = f2bf(pacc[nt][mt][r]);
                }
        }
    }
}

__global__ __launch_bounds__(256) void attn_kernel(
    const unsigned short* __restrict__ q, const unsigned short* __restrict__ k,
    const unsigned short* __restrict__ vt, float* __restrict__ out)
{
    __shared__ unsigned short ks[64 * 72];   // K tile, row-major [t][h]
    __shared__ unsigned short vs[64 * 72];   // vT tile, [h][t]
    __shared__ unsigned short ps[64 * 76];   // P round-trip, rows 16*wave..

    const int tid  = threadIdx.x;
    const int wave = tid >> 6;
    const int lane = tid & 63;
    const int l15  = lane & 15;
    const int quad = lane >> 4;
    const int pr   = blockIdx.x;             // pair (pr, 7-pr): 9 kv-tiles total
    const int b    = blockIdx.y;
    const size_t base = (size_t)b * TB * HH;
    const int qtA = pr;

    // staging address mapping (fixed per thread)
    const int r0 = tid >> 3,          c80 = (tid & 7) * 8;
    const int r1 = (tid + 256) >> 3,  c81 = (tid & 7) * 8;   // rows 32..63

    // ---- prefetch tile it=0 (k0 = 0) ----
    bf16x8 kr0 = *(const bf16x8*)(k + base + (size_t)r0 * HH + c80);
    bf16x8 kr1 = *(const bf16x8*)(k + base + (size_t)r1 * HH + c81);
    bf16x8 vr0 = *(const bf16x8*)(vt + base + (size_t)r0 * TB + c80);
    bf16x8 vr1 = *(const bf16x8*)(vt + base + (size_t)r1 * TB + c81);

    // ---- pass state (pass A: qt = qtA) ----
    int qt = qtA, q0 = qtA * 64;
    const unsigned short* qrow = q + base + (size_t)(q0 + 16 * wave + l15) * HH;
    bf16x8 aq0 = *(const bf16x8*)(qrow + quad * 8);
    bf16x8 aq1 = *(const bf16x8*)(qrow + 32 + quad * 8);

    f32x4 o4[4];
    float mrow[4], lrow[4];
#pragma unroll
    for (int nt = 0; nt < 4; ++nt) o4[nt] = (f32x4){0.f, 0.f, 0.f, 0.f};
#pragma unroll
    for (int r = 0; r < 4; ++r) { mrow[r] = -1e30f; lrow[r] = 0.f; }

    for (int it = 0; it < 9; ++it) {
        const int kt = (it <= qtA) ? it : it - qtA - 1;

        __syncthreads();             // prev tile's frag reads done
        *(bf16x8*)(ks + r0 * 72 + c80) = kr0;
        *(bf16x8*)(ks + r1 * 72 + c81) = kr1;
        *(bf16x8*)(vs + r0 * 72 + c80) = vr0;
        *(bf16x8*)(vs + r1 * 72 + c81) = vr1;
        __syncthreads();

        // ---- prefetch next tile (overlaps with compute below) ----
        if (it < 8) {
            const int itn = it + 1;
            const int ktn = (itn <= qtA) ? itn : itn - qtA - 1;
            const int k0n = ktn * 64;
            kr0 = *(const bf16x8*)(k + base + (size_t)(k0n + r0) * HH + c80);
            kr1 = *(const bf16x8*)(k + base + (size_t)(k0n + r1) * HH + c81);
            vr0 = *(const bf16x8*)(vt + base + (size_t)r0 * TB + k0n + c80);
            vr1 = *(const bf16x8*)(vt + base + (size_t)r1 * TB + k0n + c81);
        }

        // ---- S = Q K^T ----
        f32x4 s[4];
#pragma unroll
        for (int nt = 0; nt < 4; ++nt) {
            bf16x8 bk0 = *(const bf16x8*)(ks + (16 * nt + l15) * 72 + quad * 8);
            bf16x8 bk1 = *(const bf16x8*)(ks + (16 * nt + l15) * 72 + 32 + quad * 8);
            f32x4 z = (f32x4){0.f, 0.f, 0.f, 0.f};
            z = __builtin_amdgcn_mfma_f32_16x16x32_bf16(aq0, bk0, z, 0, 0, 0);
            z = __builtin_amdgcn_mfma_f32_16x16x32_bf16(aq1, bk1, z, 0, 0, 0);
            s[nt] = z;
        }

        // ---- scale + causal mask (diagonal tile only) ----
        const bool diag = (kt == qt);
        float mx[4];
#pragma unroll
        for (int r = 0; r < 4; ++r) mx[r] = -1e30f;
#pragma unroll
        for (int nt = 0; nt < 4; ++nt)
#pragma unroll
            for (int r = 0; r < 4; ++r) {
                float sv = s[nt][r] * SCALE;
                if (diag && (16 * nt + l15) > (16 * wave + quad * 4 + r)) sv = -1e30f;
                s[nt][r] = sv;
                mx[r] = fmaxf(mx[r], sv);
            }

        // ---- online softmax (stats in registers) ----
#pragma unroll
        for (int r = 0; r < 4; ++r) {
            mx[r] = fmaxf(mx[r], __shfl_xor(mx[r], 1));
            mx[r] = fmaxf(mx[r], __shfl_xor(mx[r], 2));
            mx[r] = fmaxf(mx[r], __shfl_xor(mx[r], 4));
            mx[r] = fmaxf(mx[r], __shfl_xor(mx[r], 8));
        }
        float alpha[4], psum[4];
#pragma unroll
        for (int r = 0; r < 4; ++r) {
            float mn = fmaxf(mrow[r], mx[r]);
            alpha[r] = __expf(mrow[r] - mn);
            mrow[r] = mn;
            psum[r] = 0.f;
        }
#pragma unroll
        for (int nt = 0; nt < 4; ++nt)
#pragma unroll
            for (int r = 0; r < 4; ++r) {
                float e = __expf(s[nt][r] - mrow[r]);
                psum[r] += e;
                ps[(16 * wave + quad * 4 + r) * 76 + 16 * nt + l15] = f2bf(e);
            }
#pragma unroll
        for (int r = 0; r < 4; ++r) {
            psum[r] += __shfl_xor(psum[r], 1);
            psum[r] += __shfl_xor(psum[r], 2);
            psum[r] += __shfl_xor(psum[r], 4);
            psum[r] += __shfl_xor(psum[r], 8);
            lrow[r] = lrow[r] * alpha[r] + psum[r];
        }
#pragma unroll
        for (int nt = 0; nt < 4; ++nt)
#pragma unroll
            for (int r = 0; r < 4; ++r) o4[nt][r] *= alpha[r];

        // ---- O += P V (P via wave-private LDS round-trip) ----
        bf16x8 ap0 = *(const bf16x8*)(ps + (16 * wave + l15) * 76 + quad * 8);
        bf16x8 ap1 = *(const bf16x8*)(ps + (16 * wave + l15) * 76 + 32 + quad * 8);
#pragma unroll
        for (int nt = 0; nt < 4; ++nt) {
            bf16x8 bv0 = *(const bf16x8*)(vs + (16 * nt + l15) * 72 + quad * 8);
            bf16x8 bv1 = *(const bf16x8*)(vs + (16 * nt + l15) * 72 + 32 + quad * 8);
            o4[nt] = __builtin_amdgcn_mfma_f32_16x16x32_bf16(ap0, bv0, o4[nt], 0, 0, 0);
            o4[nt] = __builtin_amdgcn_mfma_f32_16x16x32_bf16(ap1, bv1, o4[nt], 0, 0, 0);
        }

        // ---- pass epilogue / switch ----
        if (kt == qt) {
            float inv[4];
#pragma unroll
            for (int r = 0; r < 4; ++r) inv[r] = __builtin_amdgcn_rcpf(lrow[r]);
#pragma unroll
            for (int nt = 0; nt < 4; ++nt)
#pragma unroll
                for (int r = 0; r < 4; ++r)
                    out[base + (size_t)(q0 + 16 * wave + quad * 4 + r) * HH + 16 * nt + l15] =
                        o4[nt][r] * inv[r];
            if (it < 8) {
                // switch to pass B: qt = 7 - pr
                qt = 7 - pr; q0 = qt * 64;
                const unsigned short* qrow2 = q + base + (size_t)(q0 + 16 * wave + l15) * HH;
                aq0 = *(const bf16x8*)(qrow2 + quad * 8);
                aq1 = *(const bf16x8*)(qrow2 + 32 + quad * 8);
#pragma unroll
                for (int nt = 0; nt < 4; ++nt) o4[nt] = (f32x4){0.f, 0.f, 0.f, 0.f};
#pragma unroll
                for (int r = 0; r < 4; ++r) { mrow[r] = -1e30f; lrow[r] = 0.f; }
            }
        }
    }
}

extern "C" void kernel_launch(void* const* d_in, const int* in_sizes, int n_in,
                              void* d_out, int out_size, void* d_ws, size_t ws_size,
                              hipStream_t stream) {
    const float* x  = (const float*)d_in[0];
    const float* Wg = (const float*)d_in[1];
    const float* bg = (const float*)d_in[2];
    const float* Wk = (const float*)d_in[3];
    const float* Wq = (const float*)d_in[4];
    const float* Wv = (const float*)d_in[5];
    float* out = (float*)d_out;

    unsigned short* ws = (unsigned short*)d_ws;
    const size_t BTH = (size_t)BB * TB * HH;   // 4,194,304
    unsigned short* qo  = ws;
    unsigned short* ko  = ws + BTH;
    unsigned short* vto = ws + 2 * BTH;
    unsigned short* WgT = ws + 3 * BTH;        // 128x128
    unsigned short* WkT = WgT + 16384;         // 64x128 each
    unsigned short* WqT = WkT + 8192;
    unsigned short* WvT = WqT + 8192;          // total ws: 25.25 MB

    hipLaunchKernelGGL(prep_weights, dim3(160), dim3(256), 0, stream,
                       Wg, Wk, Wq, Wv, WgT, WkT, WqT, WvT);
    hipLaunchKernelGGL(gate_qkv_kernel, dim3(BB * TB / 128), dim3(256), 0, stream,
                       x, bg, WgT, WkT, WqT, WvT, qo, ko, vto);
    hipLaunchKernelGGL(attn_kernel, dim3(4, BB), dim3(256), 0, stream,
                       qo, ko, vto, out);
}